// Round 8
// baseline (337.270 us; speedup 1.0000x reference)
//
#include <hip/hip_runtime.h>
#include <hip/hip_bf16.h>

// GLM flash attention fwd: b=2, s=2048, nh=16, hs=64, fp32 I/O, bf16 MFMA.
// R8: XCD-pinned scheduling (blockIdx%8 -> XCD heuristic): each XCD works
// only 4 heads -> K/V packed working set 2MB/XCD fits the 4MB per-XCD L2,
// so all fragment loads are L2 hits. Depth-2 software pipeline (two Frags
// buffers, refill-after-PV, no rotation movs). Split-K (SEGC=512), additive
// no-max softmax (exp2, scale folded into packed K), atomic combine, fa_norm.

typedef __attribute__((ext_vector_type(8))) __bf16 bf16x8;
typedef __attribute__((ext_vector_type(4))) __bf16 bf16x4;
typedef __attribute__((ext_vector_type(4))) float floatx4;

#define S_LEN 2048
#define NH 16
#define HS 64
#define RS 1024                     // fp32 floats between seq positions
#define SEGC 512
#define L_ELEMS (2 * S_LEN * NH)    // 65536 fp32 l-accumulators
#define KB_ELEMS (2 * NH * S_LEN * HS)   // 4,194,304 bf16 = 8 MB
#define SCALE_LOG2E 0.18033688011112042f // 0.125 / ln(2)

#if __has_builtin(__builtin_amdgcn_exp2f)
#define EXP2(x) __builtin_amdgcn_exp2f(x)
#else
#define EXP2(x) exp2f(x)
#endif

// ---- fused pre-pass: K -> bf16 [b,h,s,d] (scaled), V -> bf16 V^T [b,h,d,s]
__global__ __launch_bounds__(256) void conv_kv(const float* __restrict__ k,
                                               const float* __restrict__ v,
                                               __bf16* __restrict__ kbuf,
                                               __bf16* __restrict__ vbuf)
{
    __shared__ __align__(16) __bf16 tile[64][72];     // [d][s], 144B rows
    const int tid = threadIdx.x;
    const int bh = blockIdx.x >> 5;                   // 32 s-tiles per (b,h)
    const int st = blockIdx.x & 31;
    const int b = bh >> 4, h = bh & 15;
    const int s0 = st * 64;

#pragma unroll
    for (int it = 0; it < 4; ++it) {
        const int idx = it * 256 + tid;
        const int s = idx >> 4, f4 = idx & 15;
        floatx4 val = *(const floatx4*)(k + ((size_t)(b * 2048 + s0 + s)) * 1024 + h * 64 + f4 * 4);
        bf16x4 w;
        w[0] = (__bf16)(val[0] * SCALE_LOG2E); w[1] = (__bf16)(val[1] * SCALE_LOG2E);
        w[2] = (__bf16)(val[2] * SCALE_LOG2E); w[3] = (__bf16)(val[3] * SCALE_LOG2E);
        *(bf16x4*)(kbuf + ((size_t)((b * 16 + h) * 2048 + s0 + s)) * 64 + f4 * 4) = w;
    }

#pragma unroll
    for (int it = 0; it < 4; ++it) {
        const int idx = it * 256 + tid;
        const int s = idx >> 4, f4 = idx & 15;
        floatx4 val = *(const floatx4*)(v + ((size_t)(b * 2048 + s0 + s)) * 1024 + h * 64 + f4 * 4);
#pragma unroll
        for (int i = 0; i < 4; ++i)
            tile[f4 * 4 + i][s] = (__bf16)val[i];
    }
    __syncthreads();
#pragma unroll
    for (int it = 0; it < 2; ++it) {
        const int idx = it * 256 + tid;
        const int d = idx >> 3, sg = idx & 7;
        bf16x8 w = *(const bf16x8*)&tile[d][sg * 8];
        *(bf16x8*)(vbuf + ((size_t)((b * 16 + h) * 64 + d)) * 2048 + s0 + sg * 8) = w;
    }
}

// ---- main kernel ----
struct Frags { bf16x8 bk[2][2]; bf16x8 bv[4]; };

__device__ __forceinline__ void loadKV(Frags& f, const __bf16* kbh,
                                       const __bf16* vth, int k0,
                                       int col, int quad) {
#pragma unroll
    for (int kg = 0; kg < 2; ++kg)
#pragma unroll
        for (int hf = 0; hf < 2; ++hf)
            f.bk[kg][hf] = *(const bf16x8*)(kbh + (size_t)(k0 + kg * 16 + col) * 64 + hf * 32 + quad * 8);
#pragma unroll
    for (int ff = 0; ff < 4; ++ff)
        f.bv[ff] = *(const bf16x8*)(vth + (size_t)(ff * 16 + col) * 2048 + k0 + quad * 8);
}

struct Ctx {
    const __bf16 *kbh, *vth;
    __bf16* pw0;          // P tiles for rg=0 / rg=1 (rg=1 at +16*40)
    bf16x8 aq[2][2];
    floatx4 o[2][4];
    float ls[2][4];
    int q0, bp, hi, col, quad;
};

__device__ __forceinline__ void step(Ctx& c, Frags& f, int k0) {
    // QK^T (K carries 0.125*log2e): 8 MFMAs
    floatx4 z = {0.f, 0.f, 0.f, 0.f};
    floatx4 s[2][2];
#pragma unroll
    for (int rg = 0; rg < 2; ++rg)
#pragma unroll
        for (int kg = 0; kg < 2; ++kg) {
            s[rg][kg] = __builtin_amdgcn_mfma_f32_16x16x32_bf16(c.aq[rg][0], f.bk[kg][0], z, 0, 0, 0);
            s[rg][kg] = __builtin_amdgcn_mfma_f32_16x16x32_bf16(c.aq[rg][1], f.bk[kg][1], s[rg][kg], 0, 0, 0);
        }

    // masked exp2 (no running max), l partials, P -> wave-private LDS
    const bool full = ((k0 + 31) <= c.q0) || ((k0 + 31) < c.bp);
#pragma unroll
    for (int rg = 0; rg < 2; ++rg) {
        __bf16* pw = c.pw0 + rg * (16 * 40);
#pragma unroll
        for (int kg = 0; kg < 2; ++kg) {
            const int kj = k0 + kg * 16 + c.col;
#pragma unroll
            for (int r = 0; r < 4; ++r) {
                const int qi = c.q0 + rg * 16 + c.quad * 4 + r;
                float e = EXP2(s[rg][kg][r]);
                float p = (full || (kj <= qi) || (kj < c.bp)) ? e : 0.f;
                c.ls[rg][r] += p;
                pw[(c.quad * 4 + r) * 40 + kg * 16 + c.col] = (__bf16)p;
            }
        }
    }

    __asm__ __volatile__("" ::: "memory");
    __builtin_amdgcn_s_waitcnt(0xC07F);   // lgkmcnt(0): P writes drained
    __asm__ __volatile__("" ::: "memory");

    // PV: A = P (b128 from LDS), B = f.bv; 8 MFMAs
    bf16x8 ap[2];
#pragma unroll
    for (int rg = 0; rg < 2; ++rg)
        ap[rg] = *(const bf16x8*)(c.pw0 + rg * (16 * 40) + c.col * 40 + c.quad * 8);
#pragma unroll
    for (int ff = 0; ff < 4; ++ff)
#pragma unroll
        for (int rg = 0; rg < 2; ++rg)
            c.o[rg][ff] = __builtin_amdgcn_mfma_f32_16x16x32_bf16(ap[rg], f.bv[ff], c.o[rg][ff], 0, 0, 0);

    __asm__ __volatile__("" ::: "memory");  // next P writes stay behind ap read

    // refill this buffer for k0+64 (consumed 2 steps later -> ~1 step of cover)
    if (k0 + 64 < c.hi) loadKV(f, c.kbh, c.vth, k0 + 64, c.col, c.quad);
}

__global__ __launch_bounds__(256, 4) void fa_part4(
    const float* __restrict__ q, const __bf16* __restrict__ kb,
    const __bf16* __restrict__ vt, const int* __restrict__ glm_mask,
    float* __restrict__ oacc, float* __restrict__ lacc)
{
    __shared__ __bf16 pt[4][2][16 * 40];   // per-wave, per-rowgroup P tiles

    const int wave = threadIdx.x >> 6, lane = threadIdx.x & 63;
    const int col = lane & 15, quad = lane >> 4;

    // XCD-pinned decomposition: bid = g*8 + x; XCD x owns heads x*4..x*4+3.
    const int x    = blockIdx.x & 7;
    const int g    = blockIdx.x >> 3;             // 256 per XCD
    const int head = x * 4 + (g & 3);
    const int rest = g >> 2;                      // 64 = seg(4) x qtg(16)
    const int seg  = rest >> 4;                   // seg-major (long segs first)
    const int qtg  = 15 - (rest & 15);            // long k-ranges first
    const int b = head >> 4, h = head & 15;
    const int qt = qtg * 4 + wave;
    const int q0 = qt * 32;

    const int bp = glm_mask[b];
    int klen = q0 + 32; if (bp > klen) klen = bp;
    const int lo = seg * SEGC;
    if (lo >= klen) return;                       // no block barriers -> legal
    int hi = lo + SEGC; if (hi > klen) hi = klen;

    Ctx c;
    c.kbh = kb + ((size_t)(b * 16 + h)) * 2048 * 64;
    c.vth = vt + ((size_t)(b * 16 + h)) * 64 * 2048;
    c.pw0 = &pt[wave][0][0];
    c.q0 = q0; c.bp = bp; c.hi = hi; c.col = col; c.quad = quad;

    const size_t obase = (size_t)b * (S_LEN * RS) + h * HS;

    // Q A-frags (fp32 -> bf16): aq[rg][half], kd = half*32 + quad*8 + j
#pragma unroll
    for (int rg = 0; rg < 2; ++rg) {
        const float* qp = q + obase + (size_t)(q0 + rg * 16 + col) * RS + quad * 8;
        floatx4 a0 = *(const floatx4*)qp;
        floatx4 a1 = *(const floatx4*)(qp + 4);
        floatx4 a2 = *(const floatx4*)(qp + 32);
        floatx4 a3 = *(const floatx4*)(qp + 36);
#pragma unroll
        for (int i = 0; i < 4; ++i) {
            c.aq[rg][0][i] = (__bf16)a0[i]; c.aq[rg][0][4 + i] = (__bf16)a1[i];
            c.aq[rg][1][i] = (__bf16)a2[i]; c.aq[rg][1][4 + i] = (__bf16)a3[i];
        }
    }
#pragma unroll
    for (int rg = 0; rg < 2; ++rg)
#pragma unroll
        for (int f = 0; f < 4; ++f) {
            c.o[rg][f] = (floatx4){0.f, 0.f, 0.f, 0.f};
            c.ls[rg][f] = 0.f;
        }

    // depth-2 pipeline: two buffers, refill-after-PV inside step()
    Frags fA, fB;
    loadKV(fA, c.kbh, c.vth, lo, col, quad);
    if (lo + 32 < hi) loadKV(fB, c.kbh, c.vth, lo + 32, col, quad);

    int k0 = lo;
    while (true) {
        step(c, fA, k0); k0 += 32; if (k0 >= hi) break;
        step(c, fB, k0); k0 += 32; if (k0 >= hi) break;
    }

    // epilogue: reduce l across the 16 col-lanes, atomic combine
#pragma unroll
    for (int rg = 0; rg < 2; ++rg)
#pragma unroll
        for (int r = 0; r < 4; ++r) {
            float l = c.ls[rg][r];
            l += __shfl_xor(l, 1);
            l += __shfl_xor(l, 2);
            l += __shfl_xor(l, 4);
            l += __shfl_xor(l, 8);
            const int row = q0 + rg * 16 + quad * 4 + r;
            if (col == 0)
                unsafeAtomicAdd(lacc + ((size_t)b * S_LEN + row) * NH + h, l);
#pragma unroll
            for (int f = 0; f < 4; ++f)
                unsafeAtomicAdd(oacc + obase + (size_t)row * RS + f * 16 + col, c.o[rg][f][r]);
        }
}

__global__ __launch_bounds__(256) void fa_norm(float* __restrict__ out,
                                               const float* __restrict__ lacc,
                                               int n4)
{
    const int t = blockIdx.x * 256 + threadIdx.x;
    if (t >= n4) return;
    floatx4* o4 = (floatx4*)out;
    floatx4 val = o4[t];
    const float l = lacc[t >> 4];
    const float inv = (l > 0.f) ? (1.f / l) : 0.f;
    val[0] *= inv; val[1] *= inv; val[2] *= inv; val[3] *= inv;
    o4[t] = val;
}

extern "C" void kernel_launch(void* const* d_in, const int* in_sizes, int n_in,
                              void* d_out, int out_size, void* d_ws, size_t ws_size,
                              hipStream_t stream) {
    const float* q = (const float*)d_in[0];
    const float* k = (const float*)d_in[1];
    const float* v = (const float*)d_in[2];
    const int* glm = (const int*)d_in[3];
    float* out     = (float*)d_out;

    const size_t kb_bytes = (size_t)KB_ELEMS * 2;            // 8 MB
    __bf16* kbuf = (__bf16*)d_ws;
    __bf16* vbuf = (__bf16*)((char*)d_ws + kb_bytes);
    float* lacc  = (float*)((char*)d_ws + 2 * kb_bytes);

    hipMemsetAsync(d_out, 0, (size_t)out_size * sizeof(float), stream);
    hipMemsetAsync(lacc, 0, (size_t)L_ELEMS * sizeof(float), stream);

    hipLaunchKernelGGL(conv_kv, dim3(1024), dim3(256), 0, stream, k, v, kbuf, vbuf);
    // 8 XCDs x 4 heads x 4 segs x 16 qt-groups = 2048 blocks x 4 waves
    hipLaunchKernelGGL(fa_part4, dim3(2048), dim3(256), 0, stream,
                       q, kbuf, vbuf, glm, out, lacc);
    const int n4 = out_size / 4;
    hipLaunchKernelGGL(fa_norm, dim3((n4 + 255) / 256), dim3(256), 0, stream,
                       out, lacc, n4);
}

// Round 9
// 199.119 us; speedup vs baseline: 1.6938x; 1.6938x over previous
//
#include <hip/hip_runtime.h>
#include <hip/hip_bf16.h>

// GLM flash attention fwd: b=2, s=2048, nh=16, hs=64, fp32 I/O, bf16 MFMA.
// R9: block-cooperative LDS staging of packed K/V. 4 waves/block share one
// (b,h,seg) stream at 4 adjacent 32-row q-tiles (uniform trips -> barriers
// legal). Per 64-col chunk the block stages K(8KB)+V^T(8KB) into padded LDS
// (72-el rows, 2-way-free b128 frag reads); m97-style 1-barrier pipeline
// (ds_write at iter top, glob prefetch 2 chunks ahead). Split-K (SEGC=512),
// additive no-max softmax (exp2, scale folded into packed K), atomic
// combine, fa_norm. Memsets folded into conv_kv (3 dispatches total).

typedef __attribute__((ext_vector_type(8))) __bf16 bf16x8;
typedef __attribute__((ext_vector_type(4))) __bf16 bf16x4;
typedef __attribute__((ext_vector_type(4))) float floatx4;

#define S_LEN 2048
#define NH 16
#define HS 64
#define RS 1024                     // fp32 floats between seq positions
#define SEGC 512
#define L_ELEMS (2 * S_LEN * NH)    // 65536 fp32 l-accumulators
#define KB_ELEMS (2 * NH * S_LEN * HS)   // 4,194,304 bf16 = 8 MB
#define SCALE_LOG2E 0.18033688011112042f // 0.125 / ln(2)

#if __has_builtin(__builtin_amdgcn_exp2f)
#define EXP2(x) __builtin_amdgcn_exp2f(x)
#else
#define EXP2(x) exp2f(x)
#endif

#define MFMA(a, b, c) __builtin_amdgcn_mfma_f32_16x16x32_bf16(a, b, c, 0, 0, 0)

// ---- pre-pass: K -> bf16 [b,h,s,d] (scaled), V -> bf16 V^T [b,h,d,s];
// ---- also zero-initializes out and lacc (memsets folded in).
__global__ __launch_bounds__(256) void conv_kv(const float* __restrict__ k,
                                               const float* __restrict__ v,
                                               __bf16* __restrict__ kbuf,
                                               __bf16* __restrict__ vbuf,
                                               float* __restrict__ out,
                                               float* __restrict__ lacc)
{
    __shared__ __align__(16) __bf16 tile[64][72];     // [d][s], 144B rows
    const int tid = threadIdx.x;
    const int gid = blockIdx.x * 256 + tid;           // 262144 threads

    // zero out (1M float4) + lacc (16K float4)
    floatx4 zz = {0.f, 0.f, 0.f, 0.f};
    floatx4* o4 = (floatx4*)out;
#pragma unroll
    for (int i = 0; i < 4; ++i) o4[(size_t)i * 262144 + gid] = zz;
    if (gid < L_ELEMS / 4) ((floatx4*)lacc)[gid] = zz;

    const int bh = blockIdx.x >> 5;                   // 32 s-tiles per (b,h)
    const int st = blockIdx.x & 31;
    const int b = bh >> 4, h = bh & 15;
    const int s0 = st * 64;

#pragma unroll
    for (int it = 0; it < 4; ++it) {
        const int idx = it * 256 + tid;
        const int s = idx >> 4, f4 = idx & 15;
        floatx4 val = *(const floatx4*)(k + ((size_t)(b * 2048 + s0 + s)) * 1024 + h * 64 + f4 * 4);
        bf16x4 w;
        w[0] = (__bf16)(val[0] * SCALE_LOG2E); w[1] = (__bf16)(val[1] * SCALE_LOG2E);
        w[2] = (__bf16)(val[2] * SCALE_LOG2E); w[3] = (__bf16)(val[3] * SCALE_LOG2E);
        *(bf16x4*)(kbuf + ((size_t)((b * 16 + h) * 2048 + s0 + s)) * 64 + f4 * 4) = w;
    }

#pragma unroll
    for (int it = 0; it < 4; ++it) {
        const int idx = it * 256 + tid;
        const int s = idx >> 4, f4 = idx & 15;
        floatx4 val = *(const floatx4*)(v + ((size_t)(b * 2048 + s0 + s)) * 1024 + h * 64 + f4 * 4);
#pragma unroll
        for (int i = 0; i < 4; ++i)
            tile[f4 * 4 + i][s] = (__bf16)val[i];
    }
    __syncthreads();
#pragma unroll
    for (int it = 0; it < 2; ++it) {
        const int idx = it * 256 + tid;
        const int d = idx >> 3, sg = idx & 7;
        bf16x8 w = *(const bf16x8*)&tile[d][sg * 8];
        *(bf16x8*)(vbuf + ((size_t)((b * 16 + h) * 64 + d)) * 2048 + s0 + sg * 8) = w;
    }
}

// ---- main kernel: 4 waves/block, shared LDS-staged K/V, 64-col chunks ----
__global__ __launch_bounds__(256, 3) void fa_part5(
    const float* __restrict__ q, const __bf16* __restrict__ kb,
    const __bf16* __restrict__ vt, const int* __restrict__ glm_mask,
    float* __restrict__ oacc, float* __restrict__ lacc)
{
    __shared__ __align__(16) __bf16 ldsK[2][64 * 72];  // [krow][kd], 144B rows
    __shared__ __align__(16) __bf16 ldsV[2][64 * 72];  // [d][kk],   144B rows
    __shared__ __align__(16) __bf16 pt[4][2][16 * 40]; // per-wave/rg P tiles

    const int tid  = threadIdx.x;
    const int wave = tid >> 6, lane = tid & 63;
    const int col  = lane & 15, quad = lane >> 4;

    // R7-proven order: seg-major, long q-ranges first, head-minor
    const int seg  = blockIdx.x >> 9;             // 0..3
    const int r_   = blockIdx.x & 511;
    const int qtg  = 15 - (r_ >> 5);              // 128-row q-group
    const int head = r_ & 31;
    const int b = head >> 4, h = head & 15;
    const int q0 = qtg * 128 + wave * 32;         // this wave's 32 q-rows

    const int bp = glm_mask[b];
    int klen = qtg * 128 + 128; if (bp > klen) klen = bp;  // block-uniform
    const int lo = seg * SEGC;
    if (lo >= klen) return;                        // uniform -> safe w/ barriers
    int hi = lo + SEGC; if (hi > klen) hi = klen;
    const int nch = (hi - lo + 63) >> 6;           // 64-col chunks (uniform)

    const __bf16* kbh = kb + ((size_t)(b * 16 + h)) * (2048 * 64);
    const __bf16* vth = vt + ((size_t)(b * 16 + h)) * (64 * 2048);
    const size_t obase = (size_t)b * (S_LEN * RS) + h * HS;

    // cooperative staging indices: 256 threads cover 64 rows x 8 granules x2
    const int srow = (tid & 15) | ((tid >> 6) << 4);   // 0..63
    const int sgrn = (tid >> 4) & 3;                   // base granule

    // Q A-frags: aq[rg][half], kd = half*32 + quad*8 + j
    bf16x8 aq[2][2];
#pragma unroll
    for (int rg = 0; rg < 2; ++rg) {
        const float* qp = q + obase + (size_t)(q0 + rg * 16 + col) * RS + quad * 8;
        floatx4 a0 = *(const floatx4*)qp;
        floatx4 a1 = *(const floatx4*)(qp + 4);
        floatx4 a2 = *(const floatx4*)(qp + 32);
        floatx4 a3 = *(const floatx4*)(qp + 36);
#pragma unroll
        for (int i = 0; i < 4; ++i) {
            aq[rg][0][i] = (__bf16)a0[i]; aq[rg][0][4 + i] = (__bf16)a1[i];
            aq[rg][1][i] = (__bf16)a2[i]; aq[rg][1][4 + i] = (__bf16)a3[i];
        }
    }

    floatx4 o[2][4];                // O C-frags: row = q0+rg*16+quad*4+r, d = f*16+col
    float ls[2][4];
#pragma unroll
    for (int rg = 0; rg < 2; ++rg)
#pragma unroll
        for (int f = 0; f < 4; ++f) {
            o[rg][f] = (floatx4){0.f, 0.f, 0.f, 0.f};
            ls[rg][f] = 0.f;
        }

    // prologue: stage chunk0 -> bufA; prefetch chunk1 -> regs
    bf16x8 kst[2], vst[2];
    {
        const __bf16* kp = kbh + (size_t)(lo + srow) * 64;
        const __bf16* vp = vth + (size_t)srow * 2048 + lo;
#pragma unroll
        for (int i = 0; i < 2; ++i) {
            kst[i] = *(const bf16x8*)(kp + (sgrn + 4 * i) * 8);
            vst[i] = *(const bf16x8*)(vp + (sgrn + 4 * i) * 8);
        }
#pragma unroll
        for (int i = 0; i < 2; ++i) {
            *(bf16x8*)(&ldsK[0][srow * 72 + (sgrn + 4 * i) * 8]) = kst[i];
            *(bf16x8*)(&ldsV[0][srow * 72 + (sgrn + 4 * i) * 8]) = vst[i];
        }
        if (nch > 1) {
#pragma unroll
            for (int i = 0; i < 2; ++i) {
                kst[i] = *(const bf16x8*)(kp + 64 * 64 + (sgrn + 4 * i) * 8);
                vst[i] = *(const bf16x8*)(vp + 64 + (sgrn + 4 * i) * 8);
            }
        }
    }
    __syncthreads();

    for (int c = 0; c < nch; ++c) {
        const int k0 = lo + c * 64;
        const int cur = c & 1;

        // 1) stage chunk c+1 (regs -> other buffer); prefetch chunk c+2
        if (c + 1 < nch) {
            const int nb = cur ^ 1;
#pragma unroll
            for (int i = 0; i < 2; ++i) {
                *(bf16x8*)(&ldsK[nb][srow * 72 + (sgrn + 4 * i) * 8]) = kst[i];
                *(bf16x8*)(&ldsV[nb][srow * 72 + (sgrn + 4 * i) * 8]) = vst[i];
            }
            if (c + 2 < nch) {
                const int k2 = k0 + 128;
                const __bf16* kp = kbh + (size_t)(k2 + srow) * 64;
                const __bf16* vp = vth + (size_t)srow * 2048 + k2;
#pragma unroll
                for (int i = 0; i < 2; ++i) {
                    kst[i] = *(const bf16x8*)(kp + (sgrn + 4 * i) * 8);
                    vst[i] = *(const bf16x8*)(vp + (sgrn + 4 * i) * 8);
                }
            }
        }

        // 2) fragment reads from the current buffers (2-way-free b128)
        const __bf16* lK = &ldsK[cur][0];
        const __bf16* lV = &ldsV[cur][0];
        bf16x8 bk[4][2], bv[4][2];
#pragma unroll
        for (int kg = 0; kg < 4; ++kg)
#pragma unroll
            for (int hf = 0; hf < 2; ++hf)
                bk[kg][hf] = *(const bf16x8*)(lK + (kg * 16 + col) * 72 + hf * 32 + quad * 8);
#pragma unroll
        for (int f = 0; f < 4; ++f)
#pragma unroll
            for (int kh = 0; kh < 2; ++kh)
                bv[f][kh] = *(const bf16x8*)(lV + (f * 16 + col) * 72 + kh * 32 + quad * 8);

        // 3) QK^T (K carries 0.125*log2e): 16 MFMAs
        floatx4 z = {0.f, 0.f, 0.f, 0.f};
        floatx4 s[2][4];
#pragma unroll
        for (int rg = 0; rg < 2; ++rg)
#pragma unroll
            for (int kg = 0; kg < 4; ++kg) {
                s[rg][kg] = MFMA(aq[rg][0], bk[kg][0], z);
                s[rg][kg] = MFMA(aq[rg][1], bk[kg][1], s[rg][kg]);
            }

        // 4) two kh passes: exp+mask -> P tile -> A-frag -> PV (8 MFMAs each)
#pragma unroll
        for (int kh = 0; kh < 2; ++kh) {
#pragma unroll
            for (int rg = 0; rg < 2; ++rg) {
                __bf16* pw = &pt[wave][rg][0];
#pragma unroll
                for (int g2 = 0; g2 < 2; ++g2) {
                    const int kj = k0 + (kh * 2 + g2) * 16 + col;
                    const bool pre = kj < bp;
#pragma unroll
                    for (int r = 0; r < 4; ++r) {
                        const int qi = q0 + rg * 16 + quad * 4 + r;
                        float e = EXP2(s[rg][kh * 2 + g2][r]);
                        float p = (pre || (kj <= qi)) ? e : 0.f;
                        ls[rg][r] += p;
                        pw[(quad * 4 + r) * 40 + g2 * 16 + col] = (__bf16)p;
                    }
                }
            }
            __asm__ __volatile__("" ::: "memory");
            __builtin_amdgcn_s_waitcnt(0xC07F);   // lgkmcnt(0): P writes drained
            __asm__ __volatile__("" ::: "memory");
#pragma unroll
            for (int rg = 0; rg < 2; ++rg) {
                bf16x8 ap = *(const bf16x8*)(&pt[wave][rg][0] + col * 40 + quad * 8);
#pragma unroll
                for (int f = 0; f < 4; ++f)
                    o[rg][f] = MFMA(ap, bv[f][kh], o[rg][f]);
            }
            __asm__ __volatile__("" ::: "memory");  // next P writes stay behind ap
        }

        __syncthreads();   // staged writes visible; WAR-protects both buffers
    }

    // epilogue: reduce l across the 16 col-lanes, atomic combine
#pragma unroll
    for (int rg = 0; rg < 2; ++rg)
#pragma unroll
        for (int r = 0; r < 4; ++r) {
            float l = ls[rg][r];
            l += __shfl_xor(l, 1);
            l += __shfl_xor(l, 2);
            l += __shfl_xor(l, 4);
            l += __shfl_xor(l, 8);
            const int row = q0 + rg * 16 + quad * 4 + r;
            if (col == 0)
                unsafeAtomicAdd(lacc + ((size_t)b * S_LEN + row) * NH + h, l);
#pragma unroll
            for (int f = 0; f < 4; ++f)
                unsafeAtomicAdd(oacc + obase + (size_t)row * RS + f * 16 + col, o[rg][f][r]);
        }
}

__global__ __launch_bounds__(256) void fa_norm(float* __restrict__ out,
                                               const float* __restrict__ lacc,
                                               int n4)
{
    const int t = blockIdx.x * 256 + threadIdx.x;
    if (t >= n4) return;
    floatx4* o4 = (floatx4*)out;
    floatx4 val = o4[t];
    const float l = lacc[t >> 4];
    const float inv = (l > 0.f) ? (1.f / l) : 0.f;
    val[0] *= inv; val[1] *= inv; val[2] *= inv; val[3] *= inv;
    o4[t] = val;
}

extern "C" void kernel_launch(void* const* d_in, const int* in_sizes, int n_in,
                              void* d_out, int out_size, void* d_ws, size_t ws_size,
                              hipStream_t stream) {
    const float* q = (const float*)d_in[0];
    const float* k = (const float*)d_in[1];
    const float* v = (const float*)d_in[2];
    const int* glm = (const int*)d_in[3];
    float* out     = (float*)d_out;

    const size_t kb_bytes = (size_t)KB_ELEMS * 2;            // 8 MB
    __bf16* kbuf = (__bf16*)d_ws;
    __bf16* vbuf = (__bf16*)((char*)d_ws + kb_bytes);
    float* lacc  = (float*)((char*)d_ws + 2 * kb_bytes);

    hipLaunchKernelGGL(conv_kv, dim3(1024), dim3(256), 0, stream,
                       k, v, kbuf, vbuf, out, lacc);
    // 4 segs x 16 qt-groups x 32 heads = 2048 blocks x 4 waves
    hipLaunchKernelGGL(fa_part5, dim3(2048), dim3(256), 0, stream,
                       q, kbuf, vbuf, glm, out, lacc);
    const int n4 = out_size / 4;                             // 1,048,576
    hipLaunchKernelGGL(fa_norm, dim3((n4 + 255) / 256), dim3(256), 0, stream,
                       out, lacc, n4);
}